// Round 1
// baseline (955.506 us; speedup 1.0000x reference)
//
#include <hip/hip_runtime.h>
#include <hip/hip_bf16.h>

// Problem constants (B=32, D=256, H=W=64, K=6, CTX=256, TEMP=0.5)
#define NB 32
#define ND 256
#define NN_ 4096
#define NK 6

typedef short bf16x8 __attribute__((ext_vector_type(8)));
typedef float f32x4 __attribute__((ext_vector_type(4)));

__device__ __forceinline__ float bf2f(unsigned int u) {
    union { unsigned int i; float f; } v; v.i = (u & 0xffffu) << 16; return v.f;
}
__device__ __forceinline__ unsigned short f2bf(float f) {
    __hip_bfloat16 h = __float2bfloat16(f);
    return *reinterpret_cast<unsigned short*>(&h);
}
__device__ __forceinline__ float gelu_exact(float x) {
    return 0.5f * x * (1.0f + erff(x * 0.70710678118654752f));
}

// ---------------- setup: weights->bf16, init mask/accs/state, context MLP,
// and q for step 0 (LN(clue0 + 0) @ q_w) ----------------
__global__ void k_setup(const float* __restrict__ kw, const float* __restrict__ vw,
                        unsigned short* __restrict__ kwb, unsigned short* __restrict__ vwb,
                        float* __restrict__ mask, float* __restrict__ accs,
                        float* __restrict__ state,
                        const float* __restrict__ tc, const float* __restrict__ w1,
                        const float* __restrict__ b1, const float* __restrict__ w2,
                        const float* __restrict__ b2, float* __restrict__ clue,
                        const float* __restrict__ qn_g, const float* __restrict__ qn_b,
                        const float* __restrict__ q_w, const float* __restrict__ q_b,
                        float* __restrict__ qbuf) {
    __shared__ __align__(16) float tcs[256];
    __shared__ __align__(16) float h1[256];
    __shared__ float sred[8];
    int blk = blockIdx.x, t = threadIdx.x;
    if (blk < 1059) {
        int i = blk * 256 + t;
        if (i < 65536) kwb[i] = f2bf(kw[i]);
        else if (i < 131072) vwb[i - 65536] = f2bf(vw[i - 65536]);
        else if (i < 262144) mask[i - 131072] = 1.f;
        else if (i < 262912) accs[i - 262144] = 0.f;     // [6][4][32]
        else state[i - 262912] = 0.f;                    // [32][256] h(0)=0
        return;
    }
    int b = blk - 1059;
    int lane = t & 63, wv = t >> 6;
    tcs[t] = tc[b * 256 + t];
    __syncthreads();
    const float4* wr1 = (const float4*)(w1 + (size_t)t * 256);
    const float4* xs1 = (const float4*)tcs;
    float acc = b1[t];
#pragma unroll 8
    for (int i = 0; i < 64; ++i) {
        float4 w = wr1[i], x = xs1[i];
        acc += w.x * x.x + w.y * x.y + w.z * x.z + w.w * x.w;
    }
    __syncthreads();
    h1[t] = gelu_exact(acc);
    __syncthreads();
    const float4* hs = (const float4*)h1;
    float x0 = 0.f;
    for (int r = 0; r < 6; ++r) {
        int row = r * 256 + t;
        const float4* w2r = (const float4*)(w2 + (size_t)row * 256);
        float a2 = b2[row];
#pragma unroll 8
        for (int i = 0; i < 64; ++i) {
            float4 w = w2r[i], x = hs[i];
            a2 += w.x * x.x + w.y * x.y + w.z * x.z + w.w * x.w;
        }
        float cv = fminf(fmaxf(a2, -10.f), 10.f);
        clue[b * 1536 + row] = cv;
        if (r == 0) x0 = cv;
    }
    // LN(x0) + q projection for step 0 (h=0)
    float s = x0, s2 = x0 * x0;
#pragma unroll
    for (int off = 32; off > 0; off >>= 1) {
        s += __shfl_down(s, off, 64);
        s2 += __shfl_down(s2, off, 64);
    }
    if (lane == 0) { sred[wv] = s; sred[4 + wv] = s2; }
    __syncthreads();
    float mu = (sred[0] + sred[1] + sred[2] + sred[3]) * (1.f / 256.f);
    float var = (sred[4] + sred[5] + sred[6] + sred[7]) * (1.f / 256.f) - mu * mu;
    float rs = rsqrtf(var + 1e-5f);
    tcs[t] = (x0 - mu) * rs * qn_g[t] + qn_b[t];     // reuse tcs as qln
    __syncthreads();
    const float4* wr = (const float4*)(q_w + (size_t)t * 256);
    const float4* xs = (const float4*)tcs;
    float qv = q_b[t];
#pragma unroll 8
    for (int i = 0; i < 64; ++i) {
        float4 w = wr[i], xx = xs[i];
        qv += w.x * xx.x + w.y * xx.y + w.z * xx.z + w.w * xx.w;
    }
    qbuf[b * 256 + t] = qv;
}

// ---------------- fused transpose + LN + K/V projection (bf16 MFMA) ----------------
// 64-row tiles, 32 KB LDS -> 4 blocks/CU (16 waves) for latency hiding.
// bfrag held as [2][8] (64 VGPR) with q-dim looped twice to stay <=128 VGPR.
// Output layout d-tile-major: kp/vp[(b*16+dt)*4096 + n][16 shorts] -> each wave's
// store for a (mat,dtl,q) is one contiguous 512 B block (no write amplification).
__global__ __launch_bounds__(256, 4) void k_kv(
    const float* __restrict__ features, const float* __restrict__ fn_g,
    const float* __restrict__ fn_b, const unsigned short* __restrict__ kwb,
    const unsigned short* __restrict__ vwb, const float* __restrict__ kb,
    const float* __restrict__ vb, unsigned short* __restrict__ kp,
    unsigned short* __restrict__ vp) {
    int tile = blockIdx.x, b = blockIdx.y;
    int n0 = tile * 64;
    int t = threadIdx.x;

    // fragment layout: element (n,d) -> seg = (n>>4)*8 + (d>>5), pos = ((d>>3)&3)*16 + (n&15),
    // short index = (seg*64 + pos)*8 + (d&7). ds_read_b128 per (q4,ks): lane l reads
    // 16B at (seg*64+l)*16 B -> consecutive, conflict-free.
    __shared__ __align__(16) unsigned short A[16384];   // 32 KB
    unsigned int* A32 = reinterpret_cast<unsigned int*>(A);

    int dd = t & 15, nq = t >> 4;   // nq 0..15 -> rows n0 + nq*4 + k
    const float* fb = features + (size_t)b * 1048576 + n0 + nq * 4;
    unsigned int pk[8][4];
    float s[4] = {0, 0, 0, 0}, s2[4] = {0, 0, 0, 0};
#pragma unroll
    for (int p = 0; p < 8; ++p) {
        int d0 = p * 32 + dd * 2;
        float4 a0 = *reinterpret_cast<const float4*>(fb + (size_t)d0 * 4096);
        float4 a1 = *reinterpret_cast<const float4*>(fb + (size_t)(d0 + 1) * 4096);
        s[0] += a0.x + a1.x; s2[0] += a0.x * a0.x + a1.x * a1.x;
        s[1] += a0.y + a1.y; s2[1] += a0.y * a0.y + a1.y * a1.y;
        s[2] += a0.z + a1.z; s2[2] += a0.z * a0.z + a1.z * a1.z;
        s[3] += a0.w + a1.w; s2[3] += a0.w * a0.w + a1.w * a1.w;
        pk[p][0] = (unsigned int)f2bf(a0.x) | ((unsigned int)f2bf(a1.x) << 16);
        pk[p][1] = (unsigned int)f2bf(a0.y) | ((unsigned int)f2bf(a1.y) << 16);
        pk[p][2] = (unsigned int)f2bf(a0.z) | ((unsigned int)f2bf(a1.z) << 16);
        pk[p][3] = (unsigned int)f2bf(a0.w) | ((unsigned int)f2bf(a1.w) << 16);
    }
#pragma unroll
    for (int m = 1; m < 16; m <<= 1) {
#pragma unroll
        for (int k = 0; k < 4; ++k) {
            s[k] += __shfl_xor(s[k], m, 64);
            s2[k] += __shfl_xor(s2[k], m, 64);
        }
    }
    float mm[4], rr[4];
#pragma unroll
    for (int k = 0; k < 4; ++k) {
        float mean = s[k] * (1.f / 256.f);
        float var = s2[k] * (1.f / 256.f) - mean * mean;
        mm[k] = mean; rr[k] = rsqrtf(var + 1e-5f);
    }
    int qdw = dd >> 2, jw = dd & 3;
#pragma unroll
    for (int p = 0; p < 8; ++p) {
        int d0 = p * 32 + dd * 2;
        float g0 = fn_g[d0], g1 = fn_g[d0 + 1];
        float e0 = fn_b[d0], e1 = fn_b[d0 + 1];
#pragma unroll
        for (int k = 0; k < 4; ++k) {
            int ln = nq * 4 + k;
            int nt = ln >> 4, r = ln & 15;
            float x0 = bf2f(pk[p][k]);
            float x1 = bf2f(pk[p][k] >> 16);
            unsigned int lo = f2bf((x0 - mm[k]) * rr[k] * g0 + e0);
            unsigned int hi = f2bf((x1 - mm[k]) * rr[k] * g1 + e1);
            A32[((nt * 8 + p) * 64 + qdw * 16 + r) * 4 + jw] = lo | (hi << 16);
        }
    }
    __syncthreads();

    int lane = t & 63, wv = t >> 6;
    int r = lane & 15, qd = lane >> 4;
#pragma unroll
    for (int q2 = 0; q2 < 2; ++q2) {
        bf16x8 bfrag[2][8];
#pragma unroll
        for (int q = 0; q < 2; ++q)
#pragma unroll
            for (int ks = 0; ks < 8; ++ks)
                bfrag[q][ks] = *reinterpret_cast<const bf16x8*>(
                    &A[(((q2 * 2 + q) * 8 + ks) * 64 + lane) * 8]);
#pragma unroll
        for (int mat = 0; mat < 2; ++mat) {
            const unsigned short* wb = mat ? vwb : kwb;
            const float* bias = mat ? vb : kb;
            unsigned short* outp = mat ? vp : kp;
#pragma unroll
            for (int dtl = 0; dtl < 4; ++dtl) {
                int dt = wv * 4 + dtl;
                const unsigned short* wrow = wb + (size_t)(dt * 16 + r) * 256 + qd * 8;
                f32x4 acc0 = {0, 0, 0, 0}, acc1 = {0, 0, 0, 0};
#pragma unroll
                for (int ks = 0; ks < 8; ++ks) {
                    bf16x8 af = *reinterpret_cast<const bf16x8*>(wrow + ks * 32);
                    acc0 = __builtin_amdgcn_mfma_f32_16x16x32_bf16(af, bfrag[0][ks], acc0, 0, 0, 0);
                    acc1 = __builtin_amdgcn_mfma_f32_16x16x32_bf16(af, bfrag[1][ks], acc1, 0, 0, 0);
                }
                int dbase = dt * 16 + qd * 4;
                float b0_ = bias[dbase], b1_ = bias[dbase + 1];
                float b2_ = bias[dbase + 2], b3_ = bias[dbase + 3];
                f32x4 aa[2] = {acc0, acc1};
#pragma unroll
                for (int q = 0; q < 2; ++q) {
                    int n_g = n0 + (q2 * 2 + q) * 16 + r;
                    unsigned int lo = ((unsigned int)f2bf(aa[q][1] + b1_) << 16)
                                    | (unsigned int)f2bf(aa[q][0] + b0_);
                    unsigned int hi = ((unsigned int)f2bf(aa[q][3] + b3_) << 16)
                                    | (unsigned int)f2bf(aa[q][2] + b2_);
                    *reinterpret_cast<uint2*>(
                        outp + ((size_t)(b * 16 + dt) * 4096 + n_g) * 16 + qd * 4)
                        = make_uint2(lo, hi);
                }
            }
        }
    }
}

// ---------------- B: pure streaming scores + Sigma e*v; q precomputed in qbuf.
// c==32 blocks emit previous step's stop-logit + centroid outputs.
// Partials written per-c to pb_cur (no atomics on sumev). ----------------
__global__ __launch_bounds__(256, 4) void k_qscore(
    const float* __restrict__ qbuf, const unsigned short* __restrict__ kp,
    const unsigned short* __restrict__ vp, const float* __restrict__ mask,
    float* __restrict__ escore, float* __restrict__ accs,
    float* __restrict__ pb_cur, const float* __restrict__ pb_prev,
    const float* __restrict__ sw1, const float* __restrict__ sb1,
    const float* __restrict__ sw2, const float* __restrict__ sb2,
    float* __restrict__ out_cent, float* __restrict__ out_stop, int kstep) {
    int c = blockIdx.x, b = blockIdx.y, t = threadIdx.x;
    int lane = t & 63, wv = t >> 6;
    __shared__ __align__(16) float qs[256];
    __shared__ float ash[128];
    __shared__ __align__(16) float part[8][264];
    __shared__ float sred[8];
    if (c == 32) {   // stop head + centroid out for step kstep-1
        if (kstep == 0) return;
        int kp_ = kstep - 1;
        float inv = 1.f / accs[kp_ * 128 + b];
        float a = 0.f;
#pragma unroll
        for (int c2 = 0; c2 < 32; ++c2) a += pb_prev[((size_t)c2 * 32 + b) * 256 + t];
        qs[t] = a * inv;
        __syncthreads();
        float entv = -accs[kp_ * 128 + 96 + b] * 0.12022458674074826f; // 1/log(4096+1e-6)
        float v = 0.f;
        if (t < 128) {
            const float* wr = sw1 + (size_t)t * 257;
            float acc = sb1[t];
#pragma unroll 8
            for (int i = 0; i < 256; ++i) acc += qs[i] * wr[i];
            acc += entv * wr[256];
            v = gelu_exact(acc) * sw2[t];
        }
#pragma unroll
        for (int off = 32; off > 0; off >>= 1) v += __shfl_down(v, off, 64);
        if (lane == 0) sred[wv] = v;
        __syncthreads();
        if (t == 0) {
            float sraw = sb2[0] + sred[0] + sred[1] + sred[2] + sred[3];
            out_stop[b * 6 + kp_] = 4.f * tanhf(sraw * 0.25f);
            out_cent[(b * 6 + kp_) * 2 + 0] = accs[kp_ * 128 + 32 + b];
            out_cent[(b * 6 + kp_) * 2 + 1] = accs[kp_ * 128 + 64 + b];
        }
        return;
    }
    qs[t] = qbuf[b * 256 + t];
    __syncthreads();
    // scores: 8 lanes per row; lane l owns d-chunks 2l,2l+1 of d-tile-major layout
    int l = t & 7, rg = t >> 3;
    const float* qq = qs + l * 32;
    float dsum = 0.f;
#pragma unroll
    for (int pp = 0; pp < 4; ++pp) {
        int nl = pp * 32 + rg;
        int n = c * 128 + nl;
        const uint4* base = reinterpret_cast<const uint4*>(
            kp + ((size_t)(b * 16 + l * 2) * 4096 + n) * 16);
        uint4 r0 = base[0], r1 = base[1];
        uint4 r2 = base[8192], r3 = base[8193];   // next d-tile chunk, same row
        float dot =
              bf2f(r0.x) * qq[0]  + bf2f(r0.x >> 16) * qq[1]
            + bf2f(r0.y) * qq[2]  + bf2f(r0.y >> 16) * qq[3]
            + bf2f(r0.z) * qq[4]  + bf2f(r0.z >> 16) * qq[5]
            + bf2f(r0.w) * qq[6]  + bf2f(r0.w >> 16) * qq[7]
            + bf2f(r1.x) * qq[8]  + bf2f(r1.x >> 16) * qq[9]
            + bf2f(r1.y) * qq[10] + bf2f(r1.y >> 16) * qq[11]
            + bf2f(r1.z) * qq[12] + bf2f(r1.z >> 16) * qq[13]
            + bf2f(r1.w) * qq[14] + bf2f(r1.w >> 16) * qq[15]
            + bf2f(r2.x) * qq[16] + bf2f(r2.x >> 16) * qq[17]
            + bf2f(r2.y) * qq[18] + bf2f(r2.y >> 16) * qq[19]
            + bf2f(r2.z) * qq[20] + bf2f(r2.z >> 16) * qq[21]
            + bf2f(r2.w) * qq[22] + bf2f(r2.w >> 16) * qq[23]
            + bf2f(r3.x) * qq[24] + bf2f(r3.x >> 16) * qq[25]
            + bf2f(r3.y) * qq[26] + bf2f(r3.y >> 16) * qq[27]
            + bf2f(r3.z) * qq[28] + bf2f(r3.z >> 16) * qq[29]
            + bf2f(r3.w) * qq[30] + bf2f(r3.w >> 16) * qq[31];
        dot += __shfl_xor(dot, 1, 64);
        dot += __shfl_xor(dot, 2, 64);
        dot += __shfl_xor(dot, 4, 64);
        float sc = dot * 0.0625f + logf(mask[(size_t)b * 4096 + n]);
        sc = fminf(fmaxf(sc, -50.f), 50.f);
        float lg = fminf(fmaxf(sc * 2.f, -50.f), 50.f);   // /TEMP, TEMP=0.5
        float e = expf(lg);
        if (l == 0) {
            escore[(size_t)b * 4096 + n] = e;
            ash[nl] = e;
        }
        dsum += e;
    }
    dsum *= 0.125f;   // each e counted by 8 lanes
#pragma unroll
    for (int off = 32; off > 0; off >>= 1) dsum += __shfl_down(dsum, off, 64);
    if (lane == 0) sred[wv] = dsum;
    __syncthreads();
    if (t == 0) atomicAdd(&accs[kstep * 128 + b], sred[0] + sred[1] + sred[2] + sred[3]);
    // Sigma e*v partials: thread owns 8 consecutive d, sweeps 16 rows
    int ds_ = t & 31, noff = t >> 5;
    int dt = ds_ >> 1, qh = (ds_ & 1) * 8;
    const unsigned short* vb = vp + ((size_t)(b * 16 + dt) * 4096 + c * 128 + noff * 16) * 16 + qh;
    float a0 = 0, a1 = 0, a2 = 0, a3 = 0, a4 = 0, a5 = 0, a6 = 0, a7 = 0;
#pragma unroll 4
    for (int j = 0; j < 16; ++j) {
        uint4 rv = *reinterpret_cast<const uint4*>(vb + (size_t)j * 16);
        float w = ash[noff * 16 + j];
        a0 += w * bf2f(rv.x); a1 += w * bf2f(rv.x >> 16);
        a2 += w * bf2f(rv.y); a3 += w * bf2f(rv.y >> 16);
        a4 += w * bf2f(rv.z); a5 += w * bf2f(rv.z >> 16);
        a6 += w * bf2f(rv.w); a7 += w * bf2f(rv.w >> 16);
    }
    int dbase = ds_ * 8;
    *reinterpret_cast<float4*>(&part[noff][dbase])     = make_float4(a0, a1, a2, a3);
    *reinterpret_cast<float4*>(&part[noff][dbase + 4]) = make_float4(a4, a5, a6, a7);
    __syncthreads();
    float sum = part[0][t] + part[1][t] + part[2][t] + part[3][t]
              + part[4][t] + part[5][t] + part[6][t] + part[7][t];
    pb_cur[((size_t)c * 32 + b) * 256 + t] = sum;
}

// ---------------- C: amap/centroid/entropy/mask (128 blk) + consolidated
// GRU -> h -> LN -> q for step k+1 (32 blk, one per b) ----------------
__global__ __launch_bounds__(256, 2) void k_attn2gate(
    const float* __restrict__ escore, float* __restrict__ mask,
    float* __restrict__ accs, float* __restrict__ out_amap,
    const float* __restrict__ pbuf, float* __restrict__ state,
    const float* __restrict__ clue,
    const float* __restrict__ qn_g, const float* __restrict__ qn_b,
    const float* __restrict__ q_w, const float* __restrict__ q_b,
    const float* __restrict__ wih, const float* __restrict__ bih,
    const float* __restrict__ whh, const float* __restrict__ bhh,
    float* __restrict__ qbuf, int kstep) {
    int bb = blockIdx.x, t = threadIdx.x;
    int lane = t & 63, wv = t >> 6;
    __shared__ __align__(16) float att[256];
    __shared__ __align__(16) float st[256];
    __shared__ float sred[12];
    if (bb < 128) {
        int b = bb & 31, c = bb >> 5;
        int n4 = (c * 256 + t) * 4;
        float inv = 1.f / accs[kstep * 128 + b];
        float4 e4 = *reinterpret_cast<const float4*>(&escore[(size_t)b * 4096 + n4]);
        float4 m4 = *reinterpret_cast<const float4*>(&mask[(size_t)b * 4096 + n4]);
        float a[4] = {fmaxf(e4.x * inv, 1e-8f), fmaxf(e4.y * inv, 1e-8f),
                      fmaxf(e4.z * inv, 1e-8f), fmaxf(e4.w * inv, 1e-8f)};
        *reinterpret_cast<float4*>(&out_amap[((size_t)(b * 6 + kstep)) * 4096 + n4])
            = make_float4(a[0], a[1], a[2], a[3]);
        float mv[4] = {m4.x, m4.y, m4.z, m4.w};
        float s0 = 0.f, s1 = 0.f, s2 = 0.f;
#pragma unroll
        for (int j = 0; j < 4; ++j) {
            int n = n4 + j;
            s0 += a[j] * (float)(n >> 6);
            s1 += a[j] * (float)(n & 63);
            float ac = fmaxf(a[j], 1e-6f);
            s2 += ac * logf(ac);
            mv[j] = fmaxf(mv[j] * (1.f - 0.9f * a[j]), 1e-6f);
        }
        *reinterpret_cast<float4*>(&mask[(size_t)b * 4096 + n4])
            = make_float4(mv[0], mv[1], mv[2], mv[3]);
#pragma unroll
        for (int off = 32; off > 0; off >>= 1) {
            s0 += __shfl_down(s0, off, 64);
            s1 += __shfl_down(s1, off, 64);
            s2 += __shfl_down(s2, off, 64);
        }
        if (lane == 0) { sred[wv] = s0; sred[4 + wv] = s1; sred[8 + wv] = s2; }
        __syncthreads();
        if (t == 0) {
            atomicAdd(&accs[kstep * 128 + 32 + b], sred[0] + sred[1] + sred[2] + sred[3]);
            atomicAdd(&accs[kstep * 128 + 64 + b], sred[4] + sred[5] + sred[6] + sred[7]);
            atomicAdd(&accs[kstep * 128 + 96 + b], sred[8] + sred[9] + sred[10] + sred[11]);
        }
        return;
    }
    if (kstep == 5) return;   // h/q feed step k+1; unused after last step
    int b = bb - 128;
    float inv = 1.f / accs[kstep * 128 + b];
    float a = 0.f;
#pragma unroll
    for (int c2 = 0; c2 < 32; ++c2) a += pbuf[((size_t)c2 * 32 + b) * 256 + t];
    float hprev = state[b * 256 + t];
    att[t] = a * inv;
    st[t] = hprev;
    __syncthreads();
    const float4* av = (const float4*)att;
    const float4* sv = (const float4*)st;
    float gsum[3], hsum[3];
#pragma unroll
    for (int g = 0; g < 3; ++g) {
        int row = g * 256 + t;
        const float4* wi = (const float4*)(wih + (size_t)row * 256);
        const float4* wh = (const float4*)(whh + (size_t)row * 256);
        float ai = bih[row], ah = bhh[row];
#pragma unroll 4
        for (int i = 0; i < 64; ++i) {
            float4 w1 = wi[i], x1 = av[i];
            ai += w1.x * x1.x + w1.y * x1.y + w1.z * x1.z + w1.w * x1.w;
            float4 w2 = wh[i], x2 = sv[i];
            ah += w2.x * x2.x + w2.y * x2.y + w2.z * x2.z + w2.w * x2.w;
        }
        gsum[g] = ai; hsum[g] = ah;
    }
    float rg_ = 1.f / (1.f + expf(-(gsum[0] + hsum[0])));
    float zg  = 1.f / (1.f + expf(-(gsum[1] + hsum[1])));
    float ng  = tanhf(gsum[2] + rg_ * hsum[2]);
    float h = (1.f - zg) * ng + zg * hprev;
    state[b * 256 + t] = h;
    // LN(clue_{k+1} + h) and q projection for the next step
    float x = clue[((size_t)b * 6 + kstep + 1) * 256 + t] + h;
    float s = x, s2 = x * x;
#pragma unroll
    for (int off = 32; off > 0; off >>= 1) {
        s += __shfl_down(s, off, 64);
        s2 += __shfl_down(s2, off, 64);
    }
    if (lane == 0) { sred[wv] = s; sred[4 + wv] = s2; }
    __syncthreads();
    float mu = (sred[0] + sred[1] + sred[2] + sred[3]) * (1.f / 256.f);
    float var = (sred[4] + sred[5] + sred[6] + sred[7]) * (1.f / 256.f) - mu * mu;
    float rs = rsqrtf(var + 1e-5f);
    att[t] = (x - mu) * rs * qn_g[t] + qn_b[t];   // reuse att as qln
    __syncthreads();
    const float4* wr = (const float4*)(q_w + (size_t)t * 256);
    const float4* xs = (const float4*)att;
    float qv = q_b[t];
#pragma unroll 8
    for (int i = 0; i < 64; ++i) {
        float4 w = wr[i], xx = xs[i];
        qv += w.x * xx.x + w.y * xx.y + w.z * xx.z + w.w * xx.w;
    }
    qbuf[b * 256 + t] = qv;
}

// ---------------- tail: stop head + centroid out for step 5 ----------------
__global__ void k_stop5(const float* __restrict__ pbuf, const float* __restrict__ accs,
                        const float* __restrict__ sw1, const float* __restrict__ sb1,
                        const float* __restrict__ sw2, const float* __restrict__ sb2,
                        float* __restrict__ out_cent, float* __restrict__ out_stop) {
    int b = blockIdx.x, t = threadIdx.x;
    int lane = t & 63, wv = t >> 6;
    __shared__ __align__(16) float att[256];
    __shared__ float sred[4];
    float inv = 1.f / accs[5 * 128 + b];
    float a = 0.f;
#pragma unroll
    for (int c2 = 0; c2 < 32; ++c2) a += pbuf[((size_t)c2 * 32 + b) * 256 + t];
    att[t] = a * inv;
    __syncthreads();
    float entv = -accs[5 * 128 + 96 + b] * 0.12022458674074826f;
    float v = 0.f;
    if (t < 128) {
        const float* wr = sw1 + (size_t)t * 257;
        float acc = sb1[t];
#pragma unroll 8
        for (int i = 0; i < 256; ++i) acc += att[i] * wr[i];
        acc += entv * wr[256];
        v = gelu_exact(acc) * sw2[t];
    }
#pragma unroll
    for (int off = 32; off > 0; off >>= 1) v += __shfl_down(v, off, 64);
    if (lane == 0) sred[wv] = v;
    __syncthreads();
    if (t == 0) {
        float sraw = sb2[0] + sred[0] + sred[1] + sred[2] + sred[3];
        out_stop[b * 6 + 5] = 4.f * tanhf(sraw * 0.25f);
        out_cent[(b * 6 + 5) * 2 + 0] = accs[5 * 128 + 32 + b];
        out_cent[(b * 6 + 5) * 2 + 1] = accs[5 * 128 + 64 + b];
    }
}

extern "C" void kernel_launch(void* const* d_in, const int* in_sizes, int n_in,
                              void* d_out, int out_size, void* d_ws, size_t ws_size,
                              hipStream_t stream) {
    const float* features     = (const float*)d_in[0];
    const float* task_context = (const float*)d_in[1];
    const float* ctx_w1 = (const float*)d_in[2];
    const float* ctx_b1 = (const float*)d_in[3];
    const float* ctx_w2 = (const float*)d_in[4];
    const float* ctx_b2 = (const float*)d_in[5];
    const float* q_w = (const float*)d_in[6];
    const float* q_b = (const float*)d_in[7];
    const float* k_w = (const float*)d_in[8];
    const float* k_b = (const float*)d_in[9];
    const float* v_w = (const float*)d_in[10];
    const float* v_b = (const float*)d_in[11];
    const float* qn_g = (const float*)d_in[12];
    const float* qn_b = (const float*)d_in[13];
    const float* fn_g = (const float*)d_in[14];
    const float* fn_b = (const float*)d_in[15];
    const float* stop_w1 = (const float*)d_in[16];
    const float* stop_b1 = (const float*)d_in[17];
    const float* stop_w2 = (const float*)d_in[18];
    const float* stop_b2 = (const float*)d_in[19];
    const float* gru_wih = (const float*)d_in[20];
    const float* gru_bih = (const float*)d_in[21];
    const float* gru_whh = (const float*)d_in[22];
    const float* gru_bhh = (const float*)d_in[23];

    // workspace layout (~132 MB)
    unsigned short* kwb = (unsigned short*)d_ws;
    unsigned short* vwb = kwb + 65536;
    unsigned short* kp  = vwb + 65536;
    unsigned short* vp  = kp + (size_t)NB * NN_ * ND;
    float* clue   = (float*)(vp + (size_t)NB * NN_ * ND);
    float* state  = clue + NB * NK * ND;      // [32][256]
    float* qbuf   = state + NB * ND;          // [32][256]
    float* mask   = qbuf + NB * ND;           // [32][4096]
    float* escore = mask + NB * NN_;          // [32][4096]
    float* accs   = escore + NB * NN_;        // [6][4][32]: denom,rowc,colc,ent
    float* pbuf0  = accs + NK * 4 * NB;       // [32 c][32 b][256]
    float* pbuf1  = pbuf0 + 32 * NB * ND;

    float* out_cent = (float*)d_out;          // (B,K,2)
    float* out_amap = out_cent + NB * NK * 2; // (B,K,H,W)
    float* out_stop = out_amap + (size_t)NB * NK * NN_; // (B,K)

    float* pb[2] = {pbuf0, pbuf1};

    k_setup<<<1091, 256, 0, stream>>>(k_w, v_w, kwb, vwb, mask, accs, state,
                                      task_context, ctx_w1, ctx_b1, ctx_w2, ctx_b2, clue,
                                      qn_g, qn_b, q_w, q_b, qbuf);
    k_kv<<<dim3(64, 32), 256, 0, stream>>>(features, fn_g, fn_b, kwb, vwb, k_b, v_b, kp, vp);
    for (int k = 0; k < NK; ++k) {
        k_qscore<<<dim3(33, 32), 256, 0, stream>>>(qbuf, kp, vp, mask, escore, accs,
                                                   pb[k & 1], pb[(k + 1) & 1],
                                                   stop_w1, stop_b1, stop_w2, stop_b2,
                                                   out_cent, out_stop, k);
        k_attn2gate<<<160, 256, 0, stream>>>(escore, mask, accs, out_amap, pb[k & 1], state,
                                             clue, qn_g, qn_b, q_w, q_b,
                                             gru_wih, gru_bih, gru_whh, gru_bhh, qbuf, k);
    }
    k_stop5<<<32, 256, 0, stream>>>(pb[1], accs, stop_w1, stop_b1, stop_w2, stop_b2,
                                    out_cent, out_stop);
}

// Round 2
// 852.226 us; speedup vs baseline: 1.1212x; 1.1212x over previous
//
#include <hip/hip_runtime.h>
#include <hip/hip_bf16.h>

// Problem constants (B=32, D=256, H=W=64, K=6, CTX=256, TEMP=0.5)
#define NB 32
#define ND 256
#define NN_ 4096
#define NK 6

typedef float f32x4 __attribute__((ext_vector_type(4)));

__device__ __forceinline__ float bf2f(unsigned int u) {
    union { unsigned int i; float f; } v; v.i = (u & 0xffffu) << 16; return v.f;
}
__device__ __forceinline__ unsigned short f2bf(float f) {
    __hip_bfloat16 h = __float2bfloat16(f);
    return *reinterpret_cast<unsigned short*>(&h);
}
__device__ __forceinline__ float gelu_exact(float x) {
    return 0.5f * x * (1.0f + erff(x * 0.70710678118654752f));
}

// ---------------- setup: init mask/accs/state, kwt = k_w^T, context MLP,
// q for step 0 (LN(clue0 + 0) @ q_w) ----------------
__global__ void k_setup(float* __restrict__ mask, float* __restrict__ accs,
                        float* __restrict__ state, float* __restrict__ kwt,
                        const float* __restrict__ k_w,
                        const float* __restrict__ tc, const float* __restrict__ w1,
                        const float* __restrict__ b1, const float* __restrict__ w2,
                        const float* __restrict__ b2, float* __restrict__ clue,
                        const float* __restrict__ qn_g, const float* __restrict__ qn_b,
                        const float* __restrict__ q_w, const float* __restrict__ q_b,
                        float* __restrict__ qbuf) {
    __shared__ __align__(16) float tcs[256];
    __shared__ __align__(16) float h1[256];
    __shared__ float sred[8];
    int blk = blockIdx.x, t = threadIdx.x;
    if (blk < 803) {
        int i = blk * 256 + t;
        if (i < 131072) mask[i] = 1.f;
        else if (i < 131840) accs[i - 131072] = 0.f;     // [6][4][32]
        else if (i < 140032) state[i - 131840] = 0.f;    // [32][256] h(0)=0
        else {
            int j = i - 140032;                          // kwt[j>>8][j&255] = k_w[(j&255)][j>>8]
            kwt[j] = k_w[(size_t)(j & 255) * 256 + (j >> 8)];
        }
        return;
    }
    int b = blk - 803;
    int lane = t & 63, wv = t >> 6;
    tcs[t] = tc[b * 256 + t];
    __syncthreads();
    const float4* wr1 = (const float4*)(w1 + (size_t)t * 256);
    const float4* xs1 = (const float4*)tcs;
    float acc = b1[t];
#pragma unroll 8
    for (int i = 0; i < 64; ++i) {
        float4 w = wr1[i], x = xs1[i];
        acc += w.x * x.x + w.y * x.y + w.z * x.z + w.w * x.w;
    }
    __syncthreads();
    h1[t] = gelu_exact(acc);
    __syncthreads();
    const float4* hs = (const float4*)h1;
    float x0 = 0.f;
    for (int r = 0; r < 6; ++r) {
        int row = r * 256 + t;
        const float4* w2r = (const float4*)(w2 + (size_t)row * 256);
        float a2 = b2[row];
#pragma unroll 8
        for (int i = 0; i < 64; ++i) {
            float4 w = w2r[i], x = hs[i];
            a2 += w.x * x.x + w.y * x.y + w.z * x.z + w.w * x.w;
        }
        float cv = fminf(fmaxf(a2, -10.f), 10.f);
        clue[b * 1536 + row] = cv;
        if (r == 0) x0 = cv;
    }
    // LN(x0) + q projection for step 0 (h=0)
    float s = x0, s2 = x0 * x0;
#pragma unroll
    for (int off = 32; off > 0; off >>= 1) {
        s += __shfl_down(s, off, 64);
        s2 += __shfl_down(s2, off, 64);
    }
    if (lane == 0) { sred[wv] = s; sred[4 + wv] = s2; }
    __syncthreads();
    float mu = (sred[0] + sred[1] + sred[2] + sred[3]) * (1.f / 256.f);
    float var = (sred[4] + sred[5] + sred[6] + sred[7]) * (1.f / 256.f) - mu * mu;
    float rs = rsqrtf(var + 1e-5f);
    __syncthreads();
    tcs[t] = (x0 - mu) * rs * qn_g[t] + qn_b[t];     // reuse tcs as qln
    __syncthreads();
    const float4* wr = (const float4*)(q_w + (size_t)t * 256);
    const float4* xs = (const float4*)tcs;
    float qv = q_b[t];
#pragma unroll 8
    for (int i = 0; i < 64; ++i) {
        float4 w = wr[i], xx = xs[i];
        qv += w.x * xx.x + w.y * xx.y + w.z * xx.z + w.w * xx.w;
    }
    qbuf[b * 256 + t] = qv;
}

// ---------------- fused transpose + LN -> ft (bf16, row-major [b][n][256]) ----------
// 64-row tiles; LDS staging (padded rows) for coalesced 512 B/row global writes.
// tile==64 blocks: q'0 = kwt @ q0 and qct0 = q0 . k_b for step 0.
__global__ __launch_bounds__(256, 4) void k_ln(
    const float* __restrict__ features, const float* __restrict__ fn_g,
    const float* __restrict__ fn_b, unsigned short* __restrict__ ft,
    const float* __restrict__ qbuf, const float* __restrict__ kwt,
    const float* __restrict__ k_b, float* __restrict__ qpr,
    float* __restrict__ qct) {
    int tile = blockIdx.x, b = blockIdx.y, t = threadIdx.x;
    int lane = t & 63, wv = t >> 6;
    __shared__ __align__(16) unsigned short A[64 * 264];   // 33792 B, padded rows
    __shared__ __align__(16) float qs[256];
    __shared__ float sred[8];
    unsigned int* A32 = reinterpret_cast<unsigned int*>(A);

    if (tile == 64) {   // q' for step 0
        qs[t] = qbuf[b * 256 + t];
        __syncthreads();
        const float4* kr = (const float4*)(kwt + (size_t)t * 256);
        const float4* xs = (const float4*)qs;
        float qp = 0.f;
#pragma unroll 8
        for (int i = 0; i < 64; ++i) {
            float4 w = kr[i], x = xs[i];
            qp += w.x * x.x + w.y * x.y + w.z * x.z + w.w * x.w;
        }
        qpr[b * 256 + t] = qp;
        float ct = qs[t] * k_b[t];
#pragma unroll
        for (int off = 32; off > 0; off >>= 1) ct += __shfl_down(ct, off, 64);
        if (lane == 0) sred[wv] = ct;
        __syncthreads();
        if (t == 0) qct[b] = sred[0] + sred[1] + sred[2] + sred[3];
        return;
    }

    int n0 = tile * 64;
    int dd = t & 15, nq = t >> 4;   // rows n0 + nq*4 + k
    const float* fb = features + (size_t)b * 1048576 + n0 + nq * 4;
    unsigned int pk[8][4];
    float s[4] = {0, 0, 0, 0}, s2[4] = {0, 0, 0, 0};
#pragma unroll
    for (int p = 0; p < 8; ++p) {
        int d0 = p * 32 + dd * 2;
        float4 a0 = *reinterpret_cast<const float4*>(fb + (size_t)d0 * 4096);
        float4 a1 = *reinterpret_cast<const float4*>(fb + (size_t)(d0 + 1) * 4096);
        s[0] += a0.x + a1.x; s2[0] += a0.x * a0.x + a1.x * a1.x;
        s[1] += a0.y + a1.y; s2[1] += a0.y * a0.y + a1.y * a1.y;
        s[2] += a0.z + a1.z; s2[2] += a0.z * a0.z + a1.z * a1.z;
        s[3] += a0.w + a1.w; s2[3] += a0.w * a0.w + a1.w * a1.w;
        pk[p][0] = (unsigned int)f2bf(a0.x) | ((unsigned int)f2bf(a1.x) << 16);
        pk[p][1] = (unsigned int)f2bf(a0.y) | ((unsigned int)f2bf(a1.y) << 16);
        pk[p][2] = (unsigned int)f2bf(a0.z) | ((unsigned int)f2bf(a1.z) << 16);
        pk[p][3] = (unsigned int)f2bf(a0.w) | ((unsigned int)f2bf(a1.w) << 16);
    }
#pragma unroll
    for (int m = 1; m < 16; m <<= 1) {
#pragma unroll
        for (int k = 0; k < 4; ++k) {
            s[k] += __shfl_xor(s[k], m, 64);
            s2[k] += __shfl_xor(s2[k], m, 64);
        }
    }
    float mm[4], rr[4];
#pragma unroll
    for (int k = 0; k < 4; ++k) {
        float mean = s[k] * (1.f / 256.f);
        float var = s2[k] * (1.f / 256.f) - mean * mean;
        mm[k] = mean; rr[k] = rsqrtf(var + 1e-5f);
    }
#pragma unroll
    for (int p = 0; p < 8; ++p) {
        int d0 = p * 32 + dd * 2;
        float g0 = fn_g[d0], g1 = fn_g[d0 + 1];
        float e0 = fn_b[d0], e1 = fn_b[d0 + 1];
#pragma unroll
        for (int k = 0; k < 4; ++k) {
            int ln = nq * 4 + k;
            float x0 = bf2f(pk[p][k]);
            float x1 = bf2f(pk[p][k] >> 16);
            unsigned int lo = f2bf((x0 - mm[k]) * rr[k] * g0 + e0);
            unsigned int hi = f2bf((x1 - mm[k]) * rr[k] * g1 + e1);
            A32[ln * 132 + p * 16 + dd] = lo | (hi << 16);
        }
    }
    __syncthreads();
    // writeout: coalesced 512 B rows
    int ch = t & 31, rw = t >> 5;
    unsigned short* dst = ft + ((size_t)b * 4096 + n0) * 256;
#pragma unroll
    for (int ps = 0; ps < 8; ++ps) {
        int row = ps * 8 + rw;
        uint4 vv = *reinterpret_cast<const uint4*>(&A[row * 264 + ch * 8]);
        *reinterpret_cast<uint4*>(dst + (size_t)row * 256 + ch * 8) = vv;
    }
}

// ---------------- B: single pass over ft: scores (e) + Sigma e*f partials.
// c==32 blocks emit previous step's stop-logit + centroid outputs. ----------------
__global__ __launch_bounds__(256, 4) void k_score(
    const float* __restrict__ qpr, const float* __restrict__ qct,
    const unsigned short* __restrict__ ft, const float* __restrict__ mask,
    float* __restrict__ escore, float* __restrict__ accs,
    float* __restrict__ pbuf, const float* __restrict__ attbuf,
    const float* __restrict__ sw1, const float* __restrict__ sb1,
    const float* __restrict__ sw2, const float* __restrict__ sb2,
    float* __restrict__ out_cent, float* __restrict__ out_stop, int kstep) {
    int c = blockIdx.x, b = blockIdx.y, t = threadIdx.x;
    int lane = t & 63, wv = t >> 6;
    __shared__ __align__(16) float qs[256];
    __shared__ __align__(16) float part2[4][256];
    __shared__ float sred[8];
    if (c == 32) {   // stop head + centroid out for step kstep-1
        if (kstep == 0) return;
        int kp_ = kstep - 1;
        qs[t] = attbuf[b * 256 + t];
        __syncthreads();
        float entv = -accs[kp_ * 128 + 96 + b] * 0.12022458674074826f; // 1/log(4096+1e-6)
        float v = 0.f;
        if (t < 128) {
            const float* wr = sw1 + (size_t)t * 257;
            float acc = sb1[t];
#pragma unroll 8
            for (int i = 0; i < 256; ++i) acc += qs[i] * wr[i];
            acc += entv * wr[256];
            v = gelu_exact(acc) * sw2[t];
        }
#pragma unroll
        for (int off = 32; off > 0; off >>= 1) v += __shfl_down(v, off, 64);
        if (lane == 0) sred[wv] = v;
        __syncthreads();
        if (t == 0) {
            float sraw = sb2[0] + sred[0] + sred[1] + sred[2] + sred[3];
            out_stop[b * 6 + kp_] = 4.f * tanhf(sraw * 0.25f);
            out_cent[(b * 6 + kp_) * 2 + 0] = accs[kp_ * 128 + 32 + b];
            out_cent[(b * 6 + kp_) * 2 + 1] = accs[kp_ * 128 + 64 + b];
        }
        return;
    }
    qs[t] = qpr[b * 256 + t];
    __syncthreads();
    int l = t & 15, rg = t >> 4;        // 16 lanes per row, 16 row-groups
    float qq[16];
#pragma unroll
    for (int i = 0; i < 16; ++i) qq[i] = qs[l * 16 + i];
    float qc = qct[b];
    float acc[16];
#pragma unroll
    for (int i = 0; i < 16; ++i) acc[i] = 0.f;
    float dsum = 0.f;
    const unsigned short* fb = ft + ((size_t)b * 4096 + c * 128) * 256 + l * 16;
#pragma unroll 2
    for (int rr = 0; rr < 8; ++rr) {
        int nl = rr * 16 + rg;
        int n = c * 128 + nl;
        const uint4* p = reinterpret_cast<const uint4*>(fb + (size_t)nl * 256);
        uint4 r0 = p[0], r1 = p[1];
        float v[16];
        v[0]  = bf2f(r0.x); v[1]  = bf2f(r0.x >> 16);
        v[2]  = bf2f(r0.y); v[3]  = bf2f(r0.y >> 16);
        v[4]  = bf2f(r0.z); v[5]  = bf2f(r0.z >> 16);
        v[6]  = bf2f(r0.w); v[7]  = bf2f(r0.w >> 16);
        v[8]  = bf2f(r1.x); v[9]  = bf2f(r1.x >> 16);
        v[10] = bf2f(r1.y); v[11] = bf2f(r1.y >> 16);
        v[12] = bf2f(r1.z); v[13] = bf2f(r1.z >> 16);
        v[14] = bf2f(r1.w); v[15] = bf2f(r1.w >> 16);
        float dot = 0.f;
#pragma unroll
        for (int i = 0; i < 16; ++i) dot += v[i] * qq[i];
        dot += __shfl_xor(dot, 1, 64);
        dot += __shfl_xor(dot, 2, 64);
        dot += __shfl_xor(dot, 4, 64);
        dot += __shfl_xor(dot, 8, 64);
        float sc = (dot + qc) * 0.0625f + logf(mask[(size_t)b * 4096 + n]);
        sc = fminf(fmaxf(sc, -50.f), 50.f);
        float lg = fminf(fmaxf(sc * 2.f, -50.f), 50.f);   // /TEMP, TEMP=0.5
        float e = expf(lg);
        if (l == 0) escore[(size_t)b * 4096 + n] = e;
        dsum += e;
#pragma unroll
        for (int i = 0; i < 16; ++i) acc[i] += e * v[i];
    }
    // reduce acc across the wave's 4 row-groups (lane bits 4,5)
#pragma unroll
    for (int i = 0; i < 16; ++i) {
        acc[i] += __shfl_xor(acc[i], 16, 64);
        acc[i] += __shfl_xor(acc[i], 32, 64);
    }
    if (lane < 16) {
#pragma unroll
        for (int i4 = 0; i4 < 4; ++i4)
            *reinterpret_cast<float4*>(&part2[wv][lane * 16 + i4 * 4]) =
                make_float4(acc[i4 * 4], acc[i4 * 4 + 1], acc[i4 * 4 + 2], acc[i4 * 4 + 3]);
    }
    dsum *= 0.0625f;   // each e counted by 16 lanes
#pragma unroll
    for (int off = 32; off > 0; off >>= 1) dsum += __shfl_down(dsum, off, 64);
    if (lane == 0) sred[wv] = dsum;
    __syncthreads();
    if (t == 0) atomicAdd(&accs[kstep * 128 + b], sred[0] + sred[1] + sred[2] + sred[3]);
    float sum = part2[0][t] + part2[1][t] + part2[2][t] + part2[3][t];
    pbuf[((size_t)c * 32 + b) * 256 + t] = sum;
}

// ---------------- C: amap/centroid/entropy/mask (128 blk) + GRU block per b:
// attended = v_w @ (sev/denom) + v_b -> attbuf; GRU -> h; LN -> q; q' = kwt @ q ----
__global__ __launch_bounds__(256, 2) void k_attn2gate(
    const float* __restrict__ escore, float* __restrict__ mask,
    float* __restrict__ accs, float* __restrict__ out_amap,
    const float* __restrict__ pbuf, float* __restrict__ state,
    const float* __restrict__ clue,
    const float* __restrict__ qn_g, const float* __restrict__ qn_b,
    const float* __restrict__ q_w, const float* __restrict__ q_b,
    const float* __restrict__ v_w, const float* __restrict__ v_b,
    const float* __restrict__ wih, const float* __restrict__ bih,
    const float* __restrict__ whh, const float* __restrict__ bhh,
    const float* __restrict__ kwt, const float* __restrict__ k_b,
    float* __restrict__ attbuf, float* __restrict__ qpr,
    float* __restrict__ qct, int kstep) {
    int bb = blockIdx.x, t = threadIdx.x;
    int lane = t & 63, wv = t >> 6;
    __shared__ __align__(16) float att[256];
    __shared__ __align__(16) float st[256];
    __shared__ float sred[12];
    if (bb < 128) {
        int b = bb & 31, c = bb >> 5;
        int n4 = (c * 256 + t) * 4;
        float inv = 1.f / accs[kstep * 128 + b];
        float4 e4 = *reinterpret_cast<const float4*>(&escore[(size_t)b * 4096 + n4]);
        float4 m4 = *reinterpret_cast<const float4*>(&mask[(size_t)b * 4096 + n4]);
        float a[4] = {fmaxf(e4.x * inv, 1e-8f), fmaxf(e4.y * inv, 1e-8f),
                      fmaxf(e4.z * inv, 1e-8f), fmaxf(e4.w * inv, 1e-8f)};
        *reinterpret_cast<float4*>(&out_amap[((size_t)(b * 6 + kstep)) * 4096 + n4])
            = make_float4(a[0], a[1], a[2], a[3]);
        float mv[4] = {m4.x, m4.y, m4.z, m4.w};
        float s0 = 0.f, s1 = 0.f, s2 = 0.f;
#pragma unroll
        for (int j = 0; j < 4; ++j) {
            int n = n4 + j;
            s0 += a[j] * (float)(n >> 6);
            s1 += a[j] * (float)(n & 63);
            float ac = fmaxf(a[j], 1e-6f);
            s2 += ac * logf(ac);
            mv[j] = fmaxf(mv[j] * (1.f - 0.9f * a[j]), 1e-6f);
        }
        *reinterpret_cast<float4*>(&mask[(size_t)b * 4096 + n4])
            = make_float4(mv[0], mv[1], mv[2], mv[3]);
#pragma unroll
        for (int off = 32; off > 0; off >>= 1) {
            s0 += __shfl_down(s0, off, 64);
            s1 += __shfl_down(s1, off, 64);
            s2 += __shfl_down(s2, off, 64);
        }
        if (lane == 0) { sred[wv] = s0; sred[4 + wv] = s1; sred[8 + wv] = s2; }
        __syncthreads();
        if (t == 0) {
            atomicAdd(&accs[kstep * 128 + 32 + b], sred[0] + sred[1] + sred[2] + sred[3]);
            atomicAdd(&accs[kstep * 128 + 64 + b], sred[4] + sred[5] + sred[6] + sred[7]);
            atomicAdd(&accs[kstep * 128 + 96 + b], sred[8] + sred[9] + sred[10] + sred[11]);
        }
        return;
    }
    int b = bb - 128;
    float inv = 1.f / accs[kstep * 128 + b];
    float a = 0.f;
#pragma unroll
    for (int c2 = 0; c2 < 32; ++c2) a += pbuf[((size_t)c2 * 32 + b) * 256 + t];
    att[t] = a * inv;            // abar = Sigma a * f~
    __syncthreads();
    const float4* vw4 = (const float4*)(v_w + (size_t)t * 256);
    const float4* av0 = (const float4*)att;
    float at = v_b[t];
#pragma unroll 8
    for (int i = 0; i < 64; ++i) {
        float4 w = vw4[i], x = av0[i];
        at += w.x * x.x + w.y * x.y + w.z * x.z + w.w * x.w;
    }
    attbuf[b * 256 + t] = at;
    if (kstep == 5) return;
    float hprev = state[b * 256 + t];
    __syncthreads();
    att[t] = at; st[t] = hprev;
    __syncthreads();
    const float4* av = (const float4*)att;
    const float4* sv = (const float4*)st;
    float gsum[3], hsum[3];
#pragma unroll
    for (int g = 0; g < 3; ++g) {
        int row = g * 256 + t;
        const float4* wi = (const float4*)(wih + (size_t)row * 256);
        const float4* wh = (const float4*)(whh + (size_t)row * 256);
        float ai = bih[row], ah = bhh[row];
#pragma unroll 4
        for (int i = 0; i < 64; ++i) {
            float4 w1 = wi[i], x1 = av[i];
            ai += w1.x * x1.x + w1.y * x1.y + w1.z * x1.z + w1.w * x1.w;
            float4 w2 = wh[i], x2 = sv[i];
            ah += w2.x * x2.x + w2.y * x2.y + w2.z * x2.z + w2.w * x2.w;
        }
        gsum[g] = ai; hsum[g] = ah;
    }
    float rg_ = 1.f / (1.f + expf(-(gsum[0] + hsum[0])));
    float zg  = 1.f / (1.f + expf(-(gsum[1] + hsum[1])));
    float ng  = tanhf(gsum[2] + rg_ * hsum[2]);
    float h = (1.f - zg) * ng + zg * hprev;
    state[b * 256 + t] = h;
    // LN(clue_{k+1} + h) and q projection for the next step
    float x = clue[((size_t)b * 6 + kstep + 1) * 256 + t] + h;
    float s = x, s2 = x * x;
#pragma unroll
    for (int off = 32; off > 0; off >>= 1) {
        s += __shfl_down(s, off, 64);
        s2 += __shfl_down(s2, off, 64);
    }
    if (lane == 0) { sred[wv] = s; sred[4 + wv] = s2; }
    __syncthreads();
    float mu = (sred[0] + sred[1] + sred[2] + sred[3]) * (1.f / 256.f);
    float var = (sred[4] + sred[5] + sred[6] + sred[7]) * (1.f / 256.f) - mu * mu;
    float rs = rsqrtf(var + 1e-5f);
    __syncthreads();
    att[t] = (x - mu) * rs * qn_g[t] + qn_b[t];   // reuse att as qln
    __syncthreads();
    const float4* wr = (const float4*)(q_w + (size_t)t * 256);
    const float4* xs = (const float4*)att;
    float qv = q_b[t];
#pragma unroll 8
    for (int i = 0; i < 64; ++i) {
        float4 w = wr[i], xx = xs[i];
        qv += w.x * xx.x + w.y * xx.y + w.z * xx.z + w.w * xx.w;
    }
    __syncthreads();
    st[t] = qv;
    __syncthreads();
    const float4* kr = (const float4*)(kwt + (size_t)t * 256);
    const float4* qs4 = (const float4*)st;
    float qp = 0.f;
#pragma unroll 8
    for (int i = 0; i < 64; ++i) {
        float4 w = kr[i], xx = qs4[i];
        qp += w.x * xx.x + w.y * xx.y + w.z * xx.z + w.w * xx.w;
    }
    qpr[b * 256 + t] = qp;
    float ct = qv * k_b[t];
#pragma unroll
    for (int off = 32; off > 0; off >>= 1) ct += __shfl_down(ct, off, 64);
    if (lane == 0) sred[8 + wv] = ct;
    __syncthreads();
    if (t == 0) qct[b] = sred[8] + sred[9] + sred[10] + sred[11];
}

// ---------------- tail: stop head + centroid out for step 5 ----------------
__global__ void k_stop5(const float* __restrict__ attbuf, const float* __restrict__ accs,
                        const float* __restrict__ sw1, const float* __restrict__ sb1,
                        const float* __restrict__ sw2, const float* __restrict__ sb2,
                        float* __restrict__ out_cent, float* __restrict__ out_stop) {
    int b = blockIdx.x, t = threadIdx.x;
    int lane = t & 63, wv = t >> 6;
    __shared__ __align__(16) float att[256];
    __shared__ float sred[4];
    att[t] = attbuf[b * 256 + t];
    __syncthreads();
    float entv = -accs[5 * 128 + 96 + b] * 0.12022458674074826f;
    float v = 0.f;
    if (t < 128) {
        const float* wr = sw1 + (size_t)t * 257;
        float acc = sb1[t];
#pragma unroll 8
        for (int i = 0; i < 256; ++i) acc += att[i] * wr[i];
        acc += entv * wr[256];
        v = gelu_exact(acc) * sw2[t];
    }
#pragma unroll
    for (int off = 32; off > 0; off >>= 1) v += __shfl_down(v, off, 64);
    if (lane == 0) sred[wv] = v;
    __syncthreads();
    if (t == 0) {
        float sraw = sb2[0] + sred[0] + sred[1] + sred[2] + sred[3];
        out_stop[b * 6 + 5] = 4.f * tanhf(sraw * 0.25f);
        out_cent[(b * 6 + 5) * 2 + 0] = accs[5 * 128 + 32 + b];
        out_cent[(b * 6 + 5) * 2 + 1] = accs[5 * 128 + 64 + b];
    }
}

extern "C" void kernel_launch(void* const* d_in, const int* in_sizes, int n_in,
                              void* d_out, int out_size, void* d_ws, size_t ws_size,
                              hipStream_t stream) {
    const float* features     = (const float*)d_in[0];
    const float* task_context = (const float*)d_in[1];
    const float* ctx_w1 = (const float*)d_in[2];
    const float* ctx_b1 = (const float*)d_in[3];
    const float* ctx_w2 = (const float*)d_in[4];
    const float* ctx_b2 = (const float*)d_in[5];
    const float* q_w = (const float*)d_in[6];
    const float* q_b = (const float*)d_in[7];
    const float* k_w = (const float*)d_in[8];
    const float* k_b = (const float*)d_in[9];
    const float* v_w = (const float*)d_in[10];
    const float* v_b = (const float*)d_in[11];
    const float* qn_g = (const float*)d_in[12];
    const float* qn_b = (const float*)d_in[13];
    const float* fn_g = (const float*)d_in[14];
    const float* fn_b = (const float*)d_in[15];
    const float* stop_w1 = (const float*)d_in[16];
    const float* stop_b1 = (const float*)d_in[17];
    const float* stop_w2 = (const float*)d_in[18];
    const float* stop_b2 = (const float*)d_in[19];
    const float* gru_wih = (const float*)d_in[20];
    const float* gru_bih = (const float*)d_in[21];
    const float* gru_whh = (const float*)d_in[22];
    const float* gru_bhh = (const float*)d_in[23];

    // workspace layout (~67 MB)
    unsigned short* ft = (unsigned short*)d_ws;          // [32][4096][256] bf16
    float* kwt   = (float*)(ft + (size_t)NB * NN_ * ND); // [256][256]
    float* clue  = kwt + 65536;                          // [32][6][256]
    float* state = clue + NB * NK * ND;                  // [32][256]
    float* qbuf  = state + NB * ND;                      // [32][256]
    float* qpr   = qbuf + NB * ND;                       // [32][256]
    float* qct   = qpr + NB * ND;                        // [32]
    float* attbuf= qct + NB;                             // [32][256]
    float* mask  = attbuf + NB * ND;                     // [32][4096]
    float* escore= mask + NB * NN_;                      // [32][4096]
    float* accs  = escore + NB * NN_;                    // [6][4][32]
    float* pbuf  = accs + NK * 4 * NB;                   // [32 c][32 b][256]

    float* out_cent = (float*)d_out;          // (B,K,2)
    float* out_amap = out_cent + NB * NK * 2; // (B,K,H,W)
    float* out_stop = out_amap + (size_t)NB * NK * NN_; // (B,K)

    k_setup<<<835, 256, 0, stream>>>(mask, accs, state, kwt, k_w,
                                     task_context, ctx_w1, ctx_b1, ctx_w2, ctx_b2, clue,
                                     qn_g, qn_b, q_w, q_b, qbuf);
    k_ln<<<dim3(65, 32), 256, 0, stream>>>(features, fn_g, fn_b, ft, qbuf, kwt, k_b, qpr, qct);
    for (int k = 0; k < NK; ++k) {
        k_score<<<dim3(33, 32), 256, 0, stream>>>(qpr, qct, ft, mask, escore, accs,
                                                  pbuf, attbuf,
                                                  stop_w1, stop_b1, stop_w2, stop_b2,
                                                  out_cent, out_stop, k);
        k_attn2gate<<<160, 256, 0, stream>>>(escore, mask, accs, out_amap, pbuf, state,
                                             clue, qn_g, qn_b, q_w, q_b, v_w, v_b,
                                             gru_wih, gru_bih, gru_whh, gru_bhh,
                                             kwt, k_b, attbuf, qpr, qct, k);
    }
    k_stop5<<<32, 256, 0, stream>>>(attbuf, accs, stop_w1, stop_b1, stop_w2, stop_b2,
                                    out_cent, out_stop);
}